// Round 3
// baseline (232.089 us; speedup 1.0000x reference)
//
#include <hip/hip_runtime.h>
#include <cstdint>

#define Bb 4
#define Lseq 4096
#define Hh 1024
#define Nst 64
constexpr float LN_EPS = 1e-5f;

typedef _Float16 f16x8 __attribute__((ext_vector_type(8)));
typedef _Float16 f16x4 __attribute__((ext_vector_type(4)));
typedef float f32x4v __attribute__((ext_vector_type(4)));

// ---------------------------------------------------------------------------
// K1: transpose x [B, L, H] -> xt [B, H, L]. 64x64 tiles, float4 both ways.
// LDS stride 65 (odd): max 2-way bank aliasing (free).
// ---------------------------------------------------------------------------
__global__ __launch_bounds__(256) void k_trans(const float* __restrict__ x,
                                               float* __restrict__ xt) {
    __shared__ float tile[64 * 65];   // [h][l]
    const int h0 = blockIdx.x * 64, l0 = blockIdx.y * 64, b = blockIdx.z;
    const int c = threadIdx.x & 15, r = threadIdx.x >> 4;

    const float* src = x + ((size_t)(b * Lseq + l0 + r)) * Hh + h0 + 4 * c;
#pragma unroll
    for (int it = 0; it < 4; ++it) {
        const float4 v = *(const float4*)(src + (size_t)it * 16 * Hh);
        const int l = it * 16 + r;
        tile[(4 * c + 0) * 65 + l] = v.x;
        tile[(4 * c + 1) * 65 + l] = v.y;
        tile[(4 * c + 2) * 65 + l] = v.z;
        tile[(4 * c + 3) * 65 + l] = v.w;
    }
    __syncthreads();
    float* dst = xt + ((size_t)(b * Hh + h0 + r)) * Lseq + l0 + 4 * c;
#pragma unroll
    for (int it = 0; it < 4; ++it) {
        const float* trow = tile + (it * 16 + r) * 65 + 4 * c;
        float4 o;
        o.x = trow[0]; o.y = trow[1]; o.z = trow[2]; o.w = trow[3];
        *(float4*)(dst + (size_t)it * 16 * Lseq) = o;
    }
}

// ---------------------------------------------------------------------------
// K2: chunked block-scan via MFMA, now SELF-CONTAINED:
//  - the 5 per-h 64x64 f16 matrices are computed IN-KERNEL straight into
//    XOR-swizzled LDS (~70 transcendental ops/thread) -> kills the 40MB mats
//    write + ~68MB mats read + the precompute kernel-half + d_out aliasing.
//  - phase-2 scan: serial 64-iter LDS-RMW loop (longest dep chain in the
//    kernel, 16/64 lanes active) replaced by Kogge-Stone shuffle scan:
//    lane = chunk c, 6 shfl_up steps with precomputed w^(2^k) tables,
//    16 independent n-chains per wave (ILP covers shfl latency).
// 512 threads / 2 batches per block, grid (2, Hh), LDS 80128 -> 2 blocks/CU.
// ---------------------------------------------------------------------------
#define MR0 0        // U_re   f16 [64][64] stride 128B, XOR-swizzled
#define MI0 8192     // U_im
#define MM1 16384    // M1
#define MPR 24576    // P_re
#define MPI 32768    // P_im_neg
#define USB 40960    // 2 x { uR/S_R [64][68], uI/S_I [64][68] } stride 136B
#define SCL 75776    // scalar tables (see body)

// row0 is a multiple of 16 at every use, so (row0+col)&7 == col&7
#define MFRAG(base, row0, kk) \
    (*(const f16x8*)(sm + (((base) + ((row0) + col) * 128 + ((kk) + qd * 8) * 2) ^ ((col & 7) << 4))))

static __device__ __forceinline__ f16x8 ufrag(const unsigned char* sm, int off) {
    union { f16x8 v; f16x4 h[2]; } u;
    u.h[0] = *(const f16x4*)(sm + off);      // 8B aligned
    u.h[1] = *(const f16x4*)(sm + off + 8);
    return u.v;
}

__global__ __launch_bounds__(512, 4) void k_chunk(
    float* __restrict__ xt,
    const float* __restrict__ logA, const float* __restrict__ Aim,
    const float* __restrict__ Cre, const float* __restrict__ Cim,
    const float* __restrict__ logdt, const float* __restrict__ Dp) {
    __shared__ __align__(16) unsigned char sm[80128];
    float* lsdAr = (float*)(sm + SCL);          // [64]
    float* lsdAi = (float*)(sm + SCL + 256);    // [64]
    float* lscR  = (float*)(sm + SCL + 512);    // [64]
    float* lscI  = (float*)(sm + SCL + 768);    // [64]
    float* lsK   = (float*)(sm + SCL + 1024);   // [64]
    float* lwpR  = (float*)(sm + SCL + 1280);   // [6][64]
    float* lwpI  = (float*)(sm + SCL + 2816);   // [6][64]  (ends at 80128)

    const int tid = threadIdx.x, lane = tid & 63, wv = tid >> 6;
    const int grp = wv >> 2;          // 0..1: which batch of this block's pair
    const int wb  = wv & 3;           // row-band wave 0..3
    const int h = blockIdx.y;
    const int b = blockIdx.x * 2 + grp;   // batch 0..3
    const int col = lane & 15, qd = lane >> 4;
    const int band = wb * 16;
    const int uRo = USB + grp * 17408;
    const int uIo = uRo + 8704;

    float* xr = xt + ((size_t)b * Hh + h) * Lseq;
    const float Dp1 = 1.0f + Dp[h];

    // ---- phase-1 x loads issued FIRST: HBM latency hides under all the
    //      transcendental mats math below ----
    float4 xv0[2], xv1[2];
#pragma unroll
    for (int kh2 = 0; kh2 < 2; ++kh2) {
        const float* xp = xr + (band + col) * 64 + kh2 * 32 + qd * 8;
        xv0[kh2] = *(const float4*)(xp);
        xv1[kh2] = *(const float4*)(xp + 4);
    }

    // ---- setup: per-n scalars + w64 power tables (lanes 0..63) ----
    if (tid < 64) {
        const int n = tid, idx = h * 64 + n;
        const float ar = -__expf(logA[idx]), ai = Aim[idx];
        const float dt = __expf(logdt[h]);
        const float dAr = dt * ar, dAi = dt * ai;
        const float em = __expf(dAr);
        const float wr_ = em * __cosf(dAi), wi_ = em * __sinf(dAi);
        const float Er = wr_ - 1.0f, Ei = wi_;
        const float cr = Cre[idx], ci = Cim[idx];
        const float nr = cr * Er - ci * Ei, ni = cr * Ei + ci * Er;
        const float invd = 1.0f / (ar * ar + ai * ai);
        lsdAr[n] = dAr; lsdAi[n] = dAi;
        lscR[n] = 2.0f * ((nr * ar + ni * ai) * invd);
        lscI[n] = 2.0f * ((ni * ar - nr * ai) * invd);
        // w64 = exp(64*dA); powers w64^(2^k) by repeated complex squaring
        const float e64 = __expf(dAr * 64.0f), a64 = dAi * 64.0f;
        float wR = e64 * __cosf(a64), wI = e64 * __sinf(a64);
#pragma unroll
        for (int k = 0; k < 6; ++k) {
            lwpR[k * 64 + n] = wR;
            lwpI[k * 64 + n] = wI;
            const float nwR = fmaf(wR, wR, -wI * wI);
            wI = 2.0f * wR * wI;
            wR = nwR;
        }
    }
    __syncthreads();

    // ---- K[tau] = 2 Re(sum_n Ct_n w_n^tau): parallel over (tau, n-octet),
    //      8-lane shfl_xor reduce ----
    {
        const int tau = tid >> 3, ns0 = (tid & 7) * 8;
        const float ftau = (float)tau;
        float sum = 0.0f;
#pragma unroll
        for (int j = 0; j < 8; ++j) {
            const int n = ns0 + j;
            const float ee = __expf(lsdAr[n] * ftau), ang = lsdAi[n] * ftau;
            sum += ee * (lscR[n] * __cosf(ang) - lscI[n] * __sinf(ang));
        }
        sum += __shfl_xor(sum, 1);
        sum += __shfl_xor(sum, 2);
        sum += __shfl_xor(sum, 4);
        if ((tid & 7) == 0) lsK[tau] = sum;
    }
    __syncthreads();

    // ---- build all 5 mats into swizzled LDS: 8 elems/thread/mat ----
    {
        const int e0 = tid * 8;
        const int row = e0 >> 6;                       // const across the 8
        const int c0 = e0 & 63;
        const int sb = (e0 * 2) ^ ((row & 7) << 4);    // swizzled byte offset
        const float dAr_r = lsdAr[row], dAi_r = lsdAi[row];
        const float q = (float)(row + 1);
        f16x8 ur, ui, m1, pr, pi;
#pragma unroll
        for (int j = 0; j < 8; ++j) {
            const int cc = c0 + j;
            {   // U[n=row][tau=cc]: exp(dA*(63-cc))
                const float p = (float)(63 - cc);
                const float ee = __expf(dAr_r * p), ang = dAi_r * p;
                ur[j] = (_Float16)(ee * __cosf(ang));
                ui[j] = (_Float16)(ee * __sinf(ang));
            }
            {   // P[t=row][n=cc]: Ct_n * w_n^(row+1)
                const float ee = __expf(lsdAr[cc] * q), ang = lsdAi[cc] * q;
                const float wRq = ee * __cosf(ang), wIq = ee * __sinf(ang);
                pr[j] = (_Float16)(lscR[cc] * wRq - lscI[cc] * wIq);
                pi[j] = (_Float16)(-(lscR[cc] * wIq + lscI[cc] * wRq));
            }
            m1[j] = (cc <= row) ? (_Float16)lsK[row - cc] : (_Float16)0.0f;
        }
        *(f16x8*)(sm + MR0 + sb) = ur;
        *(f16x8*)(sm + MI0 + sb) = ui;
        *(f16x8*)(sm + MM1 + sb) = m1;
        *(f16x8*)(sm + MPR + sb) = pr;
        *(f16x8*)(sm + MPI + sb) = pi;
    }

    // convert x (loads have long since landed)
    f16x8 axk[2];
#pragma unroll
    for (int kh2 = 0; kh2 < 2; ++kh2) {
        f16x8 a;
        a[0] = (_Float16)xv0[kh2].x; a[1] = (_Float16)xv0[kh2].y;
        a[2] = (_Float16)xv0[kh2].z; a[3] = (_Float16)xv0[kh2].w;
        a[4] = (_Float16)xv1[kh2].x; a[5] = (_Float16)xv1[kh2].y;
        a[6] = (_Float16)xv1[kh2].z; a[7] = (_Float16)xv1[kh2].w;
        axk[kh2] = a;
    }
    __syncthreads();  // mats visible

    // ---- phase 1: u = X @ U^T (complex) ----
    f32x4v aR[4] = {}, aI[4] = {};
    __builtin_amdgcn_s_setprio(1);
#pragma unroll
    for (int kh2 = 0; kh2 < 2; ++kh2) {
        const int kk = kh2 * 32;
#pragma unroll
        for (int nt = 0; nt < 4; ++nt) {
            aR[nt] = __builtin_amdgcn_mfma_f32_16x16x32_f16(
                axk[kh2], MFRAG(MR0, nt * 16, kk), aR[nt], 0, 0, 0);
            aI[nt] = __builtin_amdgcn_mfma_f32_16x16x32_f16(
                axk[kh2], MFRAG(MI0, nt * 16, kk), aI[nt], 0, 0, 0);
        }
    }
    __builtin_amdgcn_s_setprio(0);
#pragma unroll
    for (int nt = 0; nt < 4; ++nt)
#pragma unroll
        for (int rg = 0; rg < 4; ++rg) {
            const int cc = band + qd * 4 + rg, n = nt * 16 + col;
            *(_Float16*)(sm + uRo + cc * 136 + n * 2) = (_Float16)aR[nt][rg];
            *(_Float16*)(sm + uIo + cc * 136 + n * 2) = (_Float16)aI[nt][rg];
        }
    __syncthreads();  // u visible

    // ---- phase 2: Kogge-Stone shuffle scan over chunks. lane = chunk c;
    //      each wave owns 16 n. Inclusive scan I[c] = u[c] + w*I[c-1] via
    //      6 shfl_up steps; exclusive S[c] = I[c-1] via one more shfl_up.
    //      In-place write is safe: each lane rewrites only its own [c][n],
    //      cross-lane dataflow is via registers. ----
    {
        const int c = lane;
#pragma unroll 8
        for (int nn = 0; nn < 16; ++nn) {
            const int n = band + nn;
            float sR = (float)*(const _Float16*)(sm + uRo + c * 136 + n * 2);
            float sI = (float)*(const _Float16*)(sm + uIo + c * 136 + n * 2);
#pragma unroll
            for (int k = 0; k < 6; ++k) {
                const float wr = lwpR[k * 64 + n], wi = lwpI[k * 64 + n];
                const float tR = __shfl_up(sR, 1 << k);
                const float tI = __shfl_up(sI, 1 << k);
                if (c >= (1 << k)) {
                    sR = fmaf(wr, tR, fmaf(-wi, tI, sR));
                    sI = fmaf(wr, tI, fmaf(wi, tR, sI));
                }
            }
            float eR = __shfl_up(sR, 1), eI = __shfl_up(sI, 1);
            if (c == 0) { eR = 0.0f; eI = 0.0f; }
            *(_Float16*)(sm + uRo + c * 136 + n * 2) = (_Float16)eR;
            *(_Float16*)(sm + uIo + c * 136 + n * 2) = (_Float16)eI;
        }
    }
    __syncthreads();  // S visible

    // ---- hoist epilogue x reads: latency hides under phase-3 MFMAs ----
    float xold[4][4];
#pragma unroll
    for (int tt = 0; tt < 4; ++tt)
#pragma unroll
        for (int rg = 0; rg < 4; ++rg)
            xold[tt][rg] = xr[(band + qd * 4 + rg) * 64 + tt * 16 + col];

    // ---- phase 3: y = X@M1^T + SR@PR^T + SI@PIneg^T ----
    f32x4v acc[4] = {};
    __builtin_amdgcn_s_setprio(1);
#pragma unroll
    for (int kh2 = 0; kh2 < 2; ++kh2) {
        const int kk = kh2 * 32;
#pragma unroll
        for (int tt = 0; tt < 4; ++tt)
            acc[tt] = __builtin_amdgcn_mfma_f32_16x16x32_f16(
                axk[kh2], MFRAG(MM1, tt * 16, kk), acc[tt], 0, 0, 0);
    }
#pragma unroll
    for (int kh2 = 0; kh2 < 2; ++kh2) {
        const int kk = kh2 * 32;
        const f16x8 as = ufrag(sm, uRo + (band + col) * 136 + (kk + qd * 8) * 2);
#pragma unroll
        for (int tt = 0; tt < 4; ++tt)
            acc[tt] = __builtin_amdgcn_mfma_f32_16x16x32_f16(
                as, MFRAG(MPR, tt * 16, kk), acc[tt], 0, 0, 0);
    }
#pragma unroll
    for (int kh2 = 0; kh2 < 2; ++kh2) {
        const int kk = kh2 * 32;
        const f16x8 az = ufrag(sm, uIo + (band + col) * 136 + (kk + qd * 8) * 2);
#pragma unroll
        for (int tt = 0; tt < 4; ++tt)
            acc[tt] = __builtin_amdgcn_mfma_f32_16x16x32_f16(
                az, MFRAG(MPI, tt * 16, kk), acc[tt], 0, 0, 0);
    }
    __builtin_amdgcn_s_setprio(0);

    // ---- epilogue: r = x*(1+D) + y, write-only ----
#pragma unroll
    for (int tt = 0; tt < 4; ++tt)
#pragma unroll
        for (int rg = 0; rg < 4; ++rg) {
            const int l = (band + qd * 4 + rg) * 64 + tt * 16 + col;
            xr[l] = fmaf(xold[tt][rg], Dp1, acc[tt][rg]);
        }
}

// ---------------------------------------------------------------------------
// K3: single-pass LayerNorm + transpose back: rt [B,H,L] -> out [B,L,H].
// float4 reads along L, float4 writes along H, shuffle-butterfly partials.
// ---------------------------------------------------------------------------
__global__ __launch_bounds__(512, 2) void k_ln(const float* __restrict__ rt,
                                               float* __restrict__ out,
                                               const float* __restrict__ lnw,
                                               const float* __restrict__ lnb) {
    __shared__ float tile[16 * 1028];
    __shared__ float ps[8 * 16], pq[8 * 16];
    __shared__ float mm[16], rs[16];
    const int b  = blockIdx.y;
    const int l0 = blockIdx.x * 16;
    const int tid = threadIdx.x;
    const int lq = tid & 3;        // l-quad: handles l = lq*4 .. lq*4+3
    const int hr = tid >> 2;       // 0..127 base row
    const int lane = tid & 63, wvv = tid >> 6;

    const float* base = rt + (size_t)b * Hh * Lseq + l0 + lq * 4;

    float s0 = 0, s1 = 0, s2 = 0, s3 = 0, q0 = 0, q1 = 0, q2 = 0, q3 = 0;
#pragma unroll
    for (int p = 0; p < 8; ++p) {
        const int row = hr + p * 128;
        const float4 v = *(const float4*)(base + (size_t)row * Lseq);
        float* tw = tile + lq * 4 * 1028 + row;
        tw[0] = v.x; tw[1028] = v.y; tw[2056] = v.z; tw[3084] = v.w;
        s0 += v.x; q0 = fmaf(v.x, v.x, q0);
        s1 += v.y; q1 = fmaf(v.y, v.y, q1);
        s2 += v.z; q2 = fmaf(v.z, v.z, q2);
        s3 += v.w; q3 = fmaf(v.w, v.w, q3);
    }
#pragma unroll
    for (int d = 4; d <= 32; d <<= 1) {
        s0 += __shfl_xor(s0, d); q0 += __shfl_xor(q0, d);
        s1 += __shfl_xor(s1, d); q1 += __shfl_xor(q1, d);
        s2 += __shfl_xor(s2, d); q2 += __shfl_xor(q2, d);
        s3 += __shfl_xor(s3, d); q3 += __shfl_xor(q3, d);
    }
    if ((lane >> 2) == 0) {   // lanes 0..3, one per lq
        float* pp = ps + wvv * 16 + lq * 4;
        float* qq = pq + wvv * 16 + lq * 4;
        pp[0] = s0; pp[1] = s1; pp[2] = s2; pp[3] = s3;
        qq[0] = q0; qq[1] = q1; qq[2] = q2; qq[3] = q3;
    }
    __syncthreads();
    if (tid < 16) {
        float s = 0.f, q = 0.f;
#pragma unroll
        for (int w = 0; w < 8; ++w) { s += ps[w * 16 + tid]; q += pq[w * 16 + tid]; }
        const float mu  = s * (1.0f / Hh);
        const float var = fmaf(-mu, mu, q * (1.0f / Hh));
        mm[tid] = mu;
        rs[tid] = rsqrtf(var + LN_EPS);
    }
    __syncthreads();

    const int hq = tid & 255, lsel = tid >> 8;
    const float4 wv4 = *(const float4*)(lnw + hq * 4);
    const float4 bv4 = *(const float4*)(lnb + hq * 4);
    float* obase = out + ((size_t)b * Lseq + l0) * Hh + hq * 4;
#pragma unroll
    for (int pl = 0; pl < 8; ++pl) {
        const int l = pl * 2 + lsel;
        const float mu = mm[l], rsg = rs[l];
        const float4 v = *(const float4*)(tile + l * 1028 + hq * 4);
        float4 o;
        o.x = fmaf((v.x - mu) * rsg, wv4.x, bv4.x);
        o.y = fmaf((v.y - mu) * rsg, wv4.y, bv4.y);
        o.z = fmaf((v.z - mu) * rsg, wv4.z, bv4.z);
        o.w = fmaf((v.w - mu) * rsg, wv4.w, bv4.w);
        *(float4*)(obase + (size_t)l * Hh) = o;
    }
}

// ---------------------------------------------------------------------------
extern "C" void kernel_launch(void* const* d_in, const int* in_sizes, int n_in,
                              void* d_out, int out_size, void* d_ws, size_t ws_size,
                              hipStream_t stream) {
    const float* x     = (const float*)d_in[0];
    const float* logA  = (const float*)d_in[1];
    const float* Aim   = (const float*)d_in[2];
    const float* Cre   = (const float*)d_in[3];
    const float* Cim   = (const float*)d_in[4];
    const float* logdt = (const float*)d_in[5];
    const float* Dp    = (const float*)d_in[6];
    const float* lnw   = (const float*)d_in[7];
    const float* lnb   = (const float*)d_in[8];
    float* out = (float*)d_out;
    float* ws  = (float*)d_ws;  // 64 MiB: xt/r [B,H,L]

    k_trans<<<dim3(Hh / 64, Lseq / 64, Bb), 256, 0, stream>>>(x, ws);
    k_chunk<<<dim3(2, Hh), 512, 0, stream>>>(ws, logA, Aim, Cre, Cim, logdt, Dp);
    k_ln<<<dim3(Lseq / 16, Bb), 512, 0, stream>>>(ws, out, lnw, lnb);
}

// Round 4
// 226.566 us; speedup vs baseline: 1.0244x; 1.0244x over previous
//
#include <hip/hip_runtime.h>
#include <cstdint>

#define Bb 4
#define Lseq 4096
#define Hh 1024
#define Nst 64
constexpr float LN_EPS = 1e-5f;

typedef _Float16 f16x8 __attribute__((ext_vector_type(8)));
typedef _Float16 f16x4 __attribute__((ext_vector_type(4)));
typedef float f32x4v __attribute__((ext_vector_type(4)));

typedef const __attribute__((address_space(1))) void* gas_vp;
typedef __attribute__((address_space(3))) void* las_vp;

// XOR-swizzle within a 64x64 f16 matrix: elem e=(row*64+col) stored at
// e ^ ((row&7)<<3)  (byte ^= ((row&7)<<4)). Written pre-swizzled by k_pre so
// identity global->LDS staging (global_load_lds) lands the swizzled layout;
// fragment reads in k_chunk apply the same XOR -> conflict-free ds_read_b128.
__device__ __forceinline__ int swz(int e) { return e ^ (((e >> 6) & 7) << 3); }

// ---------------------------------------------------------------------------
// K0+K1 fused: precompute (blocks 0..1023) overlaps transpose (blocks 1024+).
// Precompute is transcendental/VALU-bound, transpose is HBM-bound.
// Transpose now writes xt as F16 (halves write BW + chunk read BW; data is
// f16-quantized downstream anyway for MFMA).
// ---------------------------------------------------------------------------
__global__ __launch_bounds__(256) void k_pre_trans(
    const float* __restrict__ x, _Float16* __restrict__ xt,
    const float* __restrict__ logA, const float* __restrict__ Aim,
    const float* __restrict__ Cre, const float* __restrict__ Cim,
    const float* __restrict__ logdt, _Float16* __restrict__ mats,
    float* __restrict__ wwR, float* __restrict__ wwI) {
    __shared__ float tile[64 * 65];               // transpose path (16.6KB)
    __shared__ float sdAr[64], sdAi[64], scR[64], scI[64], sK[64];
    const int tid = threadIdx.x;

    if (blockIdx.x < Hh) {
        // ---------------- precompute path ----------------
        const int h = blockIdx.x;
        _Float16* g = mats + (size_t)h * 20480;

        if (tid < 64) {
            const int n = tid, idx = h * 64 + n;
            const float ar = -__expf(logA[idx]), ai = Aim[idx];
            const float dt = __expf(logdt[h]);
            const float dAr = dt * ar, dAi = dt * ai;
            const float em = __expf(dAr);
            const float wr = em * __cosf(dAi), wi = em * __sinf(dAi);
            const float Er = wr - 1.0f, Ei = wi;
            const float cr = Cre[idx], ci = Cim[idx];
            const float nr = cr * Er - ci * Ei, ni = cr * Ei + ci * Er;
            const float invd = 1.0f / (ar * ar + ai * ai);
            const float CtR = (nr * ar + ni * ai) * invd;
            const float CtI = (ni * ar - nr * ai) * invd;
            sdAr[n] = dAr; sdAi[n] = dAi;
            scR[n] = 2.0f * CtR; scI[n] = 2.0f * CtI;
            const float e64 = __expf(dAr * 64.0f), a64 = dAi * 64.0f;
            wwR[idx] = e64 * __cosf(a64);
            wwI[idx] = e64 * __sinf(a64);
        }
        __syncthreads();

        for (int e = tid; e < 4096; e += 256) {
            const int row = e >> 6, colj = e & 63;
            const int es = swz(e);
            {
                const float p = (float)(63 - colj);
                const float ee = __expf(sdAr[row] * p), ang = sdAi[row] * p;
                g[es]        = (_Float16)(ee * __cosf(ang));
                g[4096 + es] = (_Float16)(ee * __sinf(ang));
            }
            {
                const int n = colj;
                const float q = (float)(row + 1);
                const float ee = __expf(sdAr[n] * q), ang = sdAi[n] * q;
                const float wRq = ee * __cosf(ang), wIq = ee * __sinf(ang);
                g[12288 + es] = (_Float16)(scR[n] * wRq - scI[n] * wIq);
                g[16384 + es] = (_Float16)(-(scR[n] * wIq + scI[n] * wRq));
            }
        }
        if (tid < 64) {
            const float tau = (float)tid;
            float sum = 0.0f;
            for (int n = 0; n < 64; ++n) {
                const float ee = __expf(sdAr[n] * tau), ang = sdAi[n] * tau;
                sum += ee * (scR[n] * __cosf(ang) - scI[n] * __sinf(ang));
            }
            sK[tid] = sum;
        }
        __syncthreads();
        for (int e = tid; e < 4096; e += 256) {
            const int t = e >> 6, j = e & 63;
            g[8192 + swz(e)] = (j <= t) ? (_Float16)sK[t - j] : (_Float16)0.0f;
        }
    } else {
        // ---------------- transpose path (fp32 in, f16 out) ----------------
        const int tb = blockIdx.x - Hh;
        const int h0 = (tb & 15) * 64;
        const int l0 = ((tb >> 4) & 63) * 64;
        const int b  = tb >> 10;
        const int c = tid & 15, r = tid >> 4;

        const float* src = x + ((size_t)(b * Lseq + l0 + r)) * Hh + h0 + 4 * c;
#pragma unroll
        for (int it = 0; it < 4; ++it) {
            const float4 v = *(const float4*)(src + (size_t)it * 16 * Hh);
            const int l = it * 16 + r;
            tile[(4 * c + 0) * 65 + l] = v.x;
            tile[(4 * c + 1) * 65 + l] = v.y;
            tile[(4 * c + 2) * 65 + l] = v.z;
            tile[(4 * c + 3) * 65 + l] = v.w;
        }
        __syncthreads();
        _Float16* dst = xt + ((size_t)(b * Hh + h0 + r)) * Lseq + l0 + 4 * c;
#pragma unroll
        for (int it = 0; it < 4; ++it) {
            const float* trow = tile + (it * 16 + r) * 65 + 4 * c;
            f16x4 o;
            o[0] = (_Float16)trow[0]; o[1] = (_Float16)trow[1];
            o[2] = (_Float16)trow[2]; o[3] = (_Float16)trow[3];
            *(f16x4*)(dst + (size_t)it * 16 * Lseq) = o;
        }
    }
}

// ---------------------------------------------------------------------------
// K2: chunked block-scan via MFMA. 512 threads / 2 batches per block,
// grid (2, Hh), 2 blocks/CU.
//  - mats staged via ASYNC global_load_lds (identity copy of pre-swizzled
//    data) -> no VGPR round-trip, stage latency overlaps the x loads.
//  - xt is f16: phase-1 fragments are direct f16x8 loads (no convert chain),
//    x read/r write BW halved.
//  - phase-2: Kogge-Stone shuffle scan (lane = chunk c, 6 shfl_up steps with
//    w^(2^k) tables built from staged w64 by 6 complex squarings) replaces
//    the serial 64-iter LDS-RMW chain.
//  - epilogue x reads hoisted above phase-3 MFMA cluster (write-only epilogue)
//  - s_setprio(1) around MFMA clusters.
// ---------------------------------------------------------------------------
#define MR0 0        // U_re   f16 [64][64] stride 128B, XOR-swizzled
#define MI0 8192     // U_im
#define MM1 16384    // M1
#define MPR 24576    // P_re
#define MPI 32768    // P_im_neg
#define USB 40960    // 2 x { uR/S_R [64][68], uI/S_I [64][68] } stride 136B
#define WPT 75776    // lwpR [6][64], lwpI [6][64]  (ends at 78848)

// row0 is a multiple of 16 at every use, so (row0+col)&7 == col&7
#define MFRAG(base, row0, kk) \
    (*(const f16x8*)(sm + (((base) + ((row0) + col) * 128 + ((kk) + qd * 8) * 2) ^ ((col & 7) << 4))))

static __device__ __forceinline__ f16x8 ufrag(const unsigned char* sm, int off) {
    union { f16x8 v; f16x4 h[2]; } u;
    u.h[0] = *(const f16x4*)(sm + off);      // 8B aligned
    u.h[1] = *(const f16x4*)(sm + off + 8);
    return u.v;
}

__global__ __launch_bounds__(512, 4) void k_chunk(
    _Float16* __restrict__ xt, const _Float16* __restrict__ mats,
    const float* __restrict__ wwR, const float* __restrict__ wwI,
    const float* __restrict__ Dp) {
    __shared__ __align__(16) unsigned char sm[78848];
    float* lwpR = (float*)(sm + WPT);           // [6][64]
    float* lwpI = (float*)(sm + WPT + 1536);    // [6][64]

    const int tid = threadIdx.x, lane = tid & 63, wv = tid >> 6;
    const int grp = wv >> 2;          // 0..1: which batch of this block's pair
    const int wb  = wv & 3;           // row-band wave 0..3
    const int h = blockIdx.y;
    const int b = blockIdx.x * 2 + grp;   // batch 0..3
    const _Float16* g = mats + (size_t)h * 20480;
    const int col = lane & 15, qd = lane >> 4;
    const int band = wb * 16;
    const int uRo = USB + grp * 17408;
    const int uIo = uRo + 8704;

    // ---- async stage: 40KB mats, identity global->LDS (pre-swizzled) ----
#pragma unroll
    for (int it = 0; it < 5; ++it) {
        const int blk = it * 8 + wv;          // 1KB block, 0..39
        __builtin_amdgcn_global_load_lds(
            (gas_vp)((const uint4*)g + blk * 64 + lane),
            (las_vp)(sm + blk * 1024), 16, 0, 0);
    }

    const float Dp1 = 1.0f + Dp[h];
    _Float16* xr = xt + ((size_t)b * Hh + h) * Lseq;

    // ---- phase-1 x loads issued NOW: latency overlaps the mats stage ----
    f16x8 axk[2];
#pragma unroll
    for (int kh2 = 0; kh2 < 2; ++kh2)
        axk[kh2] = *(const f16x8*)(xr + (band + col) * 64 + kh2 * 32 + qd * 8);

    // ---- w64^(2^k) tables by repeated complex squaring (lanes 0..63) ----
    if (tid < 64) {
        float wR = wwR[h * 64 + tid], wI = wwI[h * 64 + tid];
#pragma unroll
        for (int k = 0; k < 6; ++k) {
            lwpR[k * 64 + tid] = wR;
            lwpI[k * 64 + tid] = wI;
            const float nwR = fmaf(wR, wR, -wI * wI);
            wI = 2.0f * wR * wI;
            wR = nwR;
        }
    }
    __syncthreads();  // mats staged (vmcnt drain) + tables visible

    // ---- phase 1: u = X @ U^T (complex) ----
    f32x4v aR[4] = {}, aI[4] = {};
    __builtin_amdgcn_s_setprio(1);
#pragma unroll
    for (int kh2 = 0; kh2 < 2; ++kh2) {
        const int kk = kh2 * 32;
#pragma unroll
        for (int nt = 0; nt < 4; ++nt) {
            aR[nt] = __builtin_amdgcn_mfma_f32_16x16x32_f16(
                axk[kh2], MFRAG(MR0, nt * 16, kk), aR[nt], 0, 0, 0);
            aI[nt] = __builtin_amdgcn_mfma_f32_16x16x32_f16(
                axk[kh2], MFRAG(MI0, nt * 16, kk), aI[nt], 0, 0, 0);
        }
    }
    __builtin_amdgcn_s_setprio(0);
#pragma unroll
    for (int nt = 0; nt < 4; ++nt)
#pragma unroll
        for (int rg = 0; rg < 4; ++rg) {
            const int cc = band + qd * 4 + rg, n = nt * 16 + col;
            *(_Float16*)(sm + uRo + cc * 136 + n * 2) = (_Float16)aR[nt][rg];
            *(_Float16*)(sm + uIo + cc * 136 + n * 2) = (_Float16)aI[nt][rg];
        }
    __syncthreads();  // u visible

    // ---- phase 2: Kogge-Stone shuffle scan over chunks. lane = chunk c;
    //      each wave owns 16 n. Inclusive I[c] = u[c] + w*I[c-1] via 6
    //      shfl_up steps; exclusive S[c] = I[c-1] via one more shfl_up.
    //      Column reads at stride 136B are 2-way bank aliasing (free). ----
    {
        const int c = lane;
#pragma unroll 8
        for (int nn = 0; nn < 16; ++nn) {
            const int n = band + nn;
            float sR = (float)*(const _Float16*)(sm + uRo + c * 136 + n * 2);
            float sI = (float)*(const _Float16*)(sm + uIo + c * 136 + n * 2);
#pragma unroll
            for (int k = 0; k < 6; ++k) {
                const float wr = lwpR[k * 64 + n], wi = lwpI[k * 64 + n];
                const float tR = __shfl_up(sR, 1 << k);
                const float tI = __shfl_up(sI, 1 << k);
                if (c >= (1 << k)) {
                    sR = fmaf(wr, tR, fmaf(-wi, tI, sR));
                    sI = fmaf(wr, tI, fmaf(wi, tR, sI));
                }
            }
            float eR = __shfl_up(sR, 1), eI = __shfl_up(sI, 1);
            if (c == 0) { eR = 0.0f; eI = 0.0f; }
            *(_Float16*)(sm + uRo + c * 136 + n * 2) = (_Float16)eR;
            *(_Float16*)(sm + uIo + c * 136 + n * 2) = (_Float16)eI;
        }
    }
    __syncthreads();  // S visible

    // ---- hoist epilogue x reads: latency hides under phase-3 MFMAs ----
    float xold[4][4];
#pragma unroll
    for (int tt = 0; tt < 4; ++tt)
#pragma unroll
        for (int rg = 0; rg < 4; ++rg)
            xold[tt][rg] = (float)xr[(band + qd * 4 + rg) * 64 + tt * 16 + col];

    // ---- phase 3: y = X@M1^T + SR@PR^T + SI@PIneg^T ----
    f32x4v acc[4] = {};
    __builtin_amdgcn_s_setprio(1);
#pragma unroll
    for (int kh2 = 0; kh2 < 2; ++kh2) {
        const int kk = kh2 * 32;
#pragma unroll
        for (int tt = 0; tt < 4; ++tt)
            acc[tt] = __builtin_amdgcn_mfma_f32_16x16x32_f16(
                axk[kh2], MFRAG(MM1, tt * 16, kk), acc[tt], 0, 0, 0);
    }
#pragma unroll
    for (int kh2 = 0; kh2 < 2; ++kh2) {
        const int kk = kh2 * 32;
        const f16x8 as = ufrag(sm, uRo + (band + col) * 136 + (kk + qd * 8) * 2);
#pragma unroll
        for (int tt = 0; tt < 4; ++tt)
            acc[tt] = __builtin_amdgcn_mfma_f32_16x16x32_f16(
                as, MFRAG(MPR, tt * 16, kk), acc[tt], 0, 0, 0);
    }
#pragma unroll
    for (int kh2 = 0; kh2 < 2; ++kh2) {
        const int kk = kh2 * 32;
        const f16x8 az = ufrag(sm, uIo + (band + col) * 136 + (kk + qd * 8) * 2);
#pragma unroll
        for (int tt = 0; tt < 4; ++tt)
            acc[tt] = __builtin_amdgcn_mfma_f32_16x16x32_f16(
                az, MFRAG(MPI, tt * 16, kk), acc[tt], 0, 0, 0);
    }
    __builtin_amdgcn_s_setprio(0);

    // ---- epilogue: r = x*(1+D) + y, write-only (f16) ----
#pragma unroll
    for (int tt = 0; tt < 4; ++tt)
#pragma unroll
        for (int rg = 0; rg < 4; ++rg) {
            const int l = (band + qd * 4 + rg) * 64 + tt * 16 + col;
            xr[l] = (_Float16)fmaf(xold[tt][rg], Dp1, acc[tt][rg]);
        }
}

// ---------------------------------------------------------------------------
// K3: single-pass LayerNorm + transpose back: rt f16 [B,H,L] -> out [B,L,H].
// f16x4 reads along L, float4 writes along H, shuffle-butterfly partials.
// ---------------------------------------------------------------------------
__global__ __launch_bounds__(512, 2) void k_ln(const _Float16* __restrict__ rt,
                                               float* __restrict__ out,
                                               const float* __restrict__ lnw,
                                               const float* __restrict__ lnb) {
    __shared__ float tile[16 * 1028];
    __shared__ float ps[8 * 16], pq[8 * 16];
    __shared__ float mm[16], rs[16];
    const int b  = blockIdx.y;
    const int l0 = blockIdx.x * 16;
    const int tid = threadIdx.x;
    const int lq = tid & 3;        // l-quad: handles l = lq*4 .. lq*4+3
    const int hr = tid >> 2;       // 0..127 base row
    const int lane = tid & 63, wvv = tid >> 6;

    const _Float16* base = rt + (size_t)b * Hh * Lseq + l0 + lq * 4;

    float s0 = 0, s1 = 0, s2 = 0, s3 = 0, q0 = 0, q1 = 0, q2 = 0, q3 = 0;
#pragma unroll
    for (int p = 0; p < 8; ++p) {
        const int row = hr + p * 128;
        const f16x4 v = *(const f16x4*)(base + (size_t)row * Lseq);
        const float vx = (float)v[0], vy = (float)v[1];
        const float vz = (float)v[2], vw = (float)v[3];
        float* tw = tile + lq * 4 * 1028 + row;
        tw[0] = vx; tw[1028] = vy; tw[2056] = vz; tw[3084] = vw;
        s0 += vx; q0 = fmaf(vx, vx, q0);
        s1 += vy; q1 = fmaf(vy, vy, q1);
        s2 += vz; q2 = fmaf(vz, vz, q2);
        s3 += vw; q3 = fmaf(vw, vw, q3);
    }
#pragma unroll
    for (int d = 4; d <= 32; d <<= 1) {
        s0 += __shfl_xor(s0, d); q0 += __shfl_xor(q0, d);
        s1 += __shfl_xor(s1, d); q1 += __shfl_xor(q1, d);
        s2 += __shfl_xor(s2, d); q2 += __shfl_xor(q2, d);
        s3 += __shfl_xor(s3, d); q3 += __shfl_xor(q3, d);
    }
    if ((lane >> 2) == 0) {   // lanes 0..3, one per lq
        float* pp = ps + wvv * 16 + lq * 4;
        float* qq = pq + wvv * 16 + lq * 4;
        pp[0] = s0; pp[1] = s1; pp[2] = s2; pp[3] = s3;
        qq[0] = q0; qq[1] = q1; qq[2] = q2; qq[3] = q3;
    }
    __syncthreads();
    if (tid < 16) {
        float s = 0.f, q = 0.f;
#pragma unroll
        for (int w = 0; w < 8; ++w) { s += ps[w * 16 + tid]; q += pq[w * 16 + tid]; }
        const float mu  = s * (1.0f / Hh);
        const float var = fmaf(-mu, mu, q * (1.0f / Hh));
        mm[tid] = mu;
        rs[tid] = rsqrtf(var + LN_EPS);
    }
    __syncthreads();

    const int hq = tid & 255, lsel = tid >> 8;
    const float4 wv4 = *(const float4*)(lnw + hq * 4);
    const float4 bv4 = *(const float4*)(lnb + hq * 4);
    float* obase = out + ((size_t)b * Lseq + l0) * Hh + hq * 4;
#pragma unroll
    for (int pl = 0; pl < 8; ++pl) {
        const int l = pl * 2 + lsel;
        const float mu = mm[l], rsg = rs[l];
        const float4 v = *(const float4*)(tile + l * 1028 + hq * 4);
        float4 o;
        o.x = fmaf((v.x - mu) * rsg, wv4.x, bv4.x);
        o.y = fmaf((v.y - mu) * rsg, wv4.y, bv4.y);
        o.z = fmaf((v.z - mu) * rsg, wv4.z, bv4.z);
        o.w = fmaf((v.w - mu) * rsg, wv4.w, bv4.w);
        *(float4*)(obase + (size_t)l * Hh) = o;
    }
}

// ---------------------------------------------------------------------------
extern "C" void kernel_launch(void* const* d_in, const int* in_sizes, int n_in,
                              void* d_out, int out_size, void* d_ws, size_t ws_size,
                              hipStream_t stream) {
    const float* x     = (const float*)d_in[0];
    const float* logA  = (const float*)d_in[1];
    const float* Aim   = (const float*)d_in[2];
    const float* Cre   = (const float*)d_in[3];
    const float* Cim   = (const float*)d_in[4];
    const float* logdt = (const float*)d_in[5];
    const float* Dp    = (const float*)d_in[6];
    const float* lnw   = (const float*)d_in[7];
    const float* lnb   = (const float*)d_in[8];
    float* out = (float*)d_out;
    _Float16* ws = (_Float16*)d_ws;  // 32 MiB of the 64 MiB ws: xt/r f16 [B,H,L]

    _Float16* mats = (_Float16*)d_out;                          // 40 MiB
    float* wwR = (float*)((char*)d_out + 41943040);             // 256 KiB
    float* wwI = (float*)((char*)d_out + 42205184);             // 256 KiB

    // precompute blocks (0..1023) overlap transpose blocks (1024..5119)
    k_pre_trans<<<dim3(Hh + (Hh / 64) * (Lseq / 64) * Bb), 256, 0, stream>>>(
        x, ws, logA, Aim, Cre, Cim, logdt, mats, wwR, wwI);
    k_chunk<<<dim3(2, Hh), 512, 0, stream>>>(ws, mats, wwR, wwI, Dp);
    k_ln<<<dim3(Lseq / 16, Bb), 512, 0, stream>>>(ws, out, lnw, lnb);
}